// Round 3
// baseline (37.259 us; speedup 1.0000x reference)
//
#include <hip/hip_runtime.h>
#include <math.h>
#include <utility>

#define DIMS  16
#define BATCH 32768
#define NPAIR 136
#define MP 160        // A rows: 136 S4 + 16 S3 + S2 + S1 + pad
#define KP 160        // K: 136 pairs + 16 x + two ones + pad
#define NB 128        // samples per block
#define NMT 5         // M-tiles of 32
#define NKK 10        // K-steps of 16
#define NNT 4         // N-tiles of 32

typedef short  s16x8  __attribute__((ext_vector_type(8)));
typedef float  f32x16 __attribute__((ext_vector_type(16)));

#define A_ELEMS (NKK*NMT*64*8)      // 25600 bf16
#define P_ELEMS (NKK*NNT*64*8)      // 20480 bf16
#define A_BYTES (A_ELEMS*2)         // 51200
#define P_BYTES (P_ELEMS*2)         // 40960
#define RED_OFF (A_BYTES + P_BYTES) // 92160 (16B aligned)
#define LDS_BYTES (RED_OFF + 8*32*4)

// ---------- compile-time combinatorics (lex = combinations_with_replacement) ----------
constexpr int pairlex(int i0, int i1) {
    int s = 0; for (int j = 0; j < i0; ++j) s += (DIMS - j); return s + (i1 - i0);
}
constexpr int cnt3(int j) { return (DIMS - j) * (DIMS + 1 - j) / 2; }
constexpr int cnt4(int j) { return (DIMS - j) * (DIMS + 1 - j) * (DIMS + 2 - j) / 6; }
constexpr int off3(int i0) { int s = 0; for (int j = 0; j < i0; ++j) s += cnt3(j); return s; }
constexpr int off4(int i0) { int s = 0; for (int j = 0; j < i0; ++j) s += cnt4(j); return s; }
constexpr int w3base(int i0) { return 1 + DIMS + NPAIR + off3(i0); }                 // 153+...
constexpr int w4base(int i0, int i1) {
    int s = off4(i0); for (int b = i0; b < i1; ++b) s += cnt3(b);
    return 1 + DIMS + NPAIR + 816 + s;                                               // 969+...
}
constexpr int pid_i0(int pid) {
    int i0 = 0, rem = pid; while (rem >= DIMS - i0) { rem -= DIMS - i0; ++i0; } return i0;
}
constexpr int pid_i1(int pid) {
    int i0 = 0, rem = pid; while (rem >= DIMS - i0) { rem -= DIMS - i0; ++i0; } return i0 + rem;
}
static_assert(pairlex(15,15) == 135 && off3(DIMS) == 816 && off4(DIMS) == 3876, "combi");
static_assert(w4base(15,15) == 4844 && w3base(15) == 968, "wtail");

// ---------- per-row metadata for building A (gates: 0=w4 1=w3 2=w2 3=w1 4=zero) ----------
// A[row][k] = (qs<=k<qe) ? gate[gs] * W[wb + k - qs] : 0
struct RowMeta { short qs, qe, wb, gs; };
struct RowTab  { RowMeta m[MP]; };
constexpr RowTab make_rowtab() {
    RowTab t{};
    for (int r = 0; r < MP; ++r) {
        RowMeta rm{0,0,0,4};
        if (r < NPAIR) {                       // S4 rows: suffix of P starting at (i1,i1)
            int i0 = pid_i0(r), i1 = pid_i1(r);
            rm = RowMeta{ (short)pairlex(i1,i1), (short)NPAIR, (short)w4base(i0,i1), 0 };
        } else if (r < NPAIR + DIMS) {         // S3 rows: suffix starting at (i0,i0)
            int i0 = r - NPAIR;
            rm = RowMeta{ (short)pairlex(i0,i0), (short)NPAIR, (short)w3base(i0), 1 };
        } else if (r == 152) {                 // S2 row: dot(W2, P)
            rm = RowMeta{ 0, (short)NPAIR, 17, 2 };
        } else if (r == 153) {                 // S1 row: dot(W1, x) via P[136..151]=x
            rm = RowMeta{ (short)NPAIR, (short)(NPAIR+DIMS), 1, 3 };
        }
        t.m[r] = rm;
    }
    return t;
}
__device__ __constant__ RowTab ROWTAB = make_rowtab();

// ---------- bf16 helpers ----------
__device__ __forceinline__ ushort f2bf(float f) {
    union { float f; unsigned u; } v{f};
    return (ushort)((v.u + 0x7FFF + ((v.u >> 16) & 1)) >> 16);   // RNE
}
__device__ __forceinline__ float bf2f(short h) {
    union { unsigned u; float f; } v{ (unsigned)(ushort)h << 16 };
    return v.f;
}

// P_frag elem offset for row r (compile-time part); layout: ((kk*4+nt)*64+lane)*8+e
// 32x32x16 B-frag: lane l -> n=l&31, k=4*(l>>5)+(e&3)+8*(e>>2)
constexpr int p_roff(int r) {
    return ((r >> 4) << 11) + (((r >> 2) & 1) << 8) + (r & 3) + (((r >> 3) & 1) << 2);
}

// ---------- static_for ----------
template<typename F, int... Is>
__device__ __forceinline__ void sfor_impl(F&& f, std::integer_sequence<int, Is...>) {
    (f(std::integral_constant<int, Is>{}), ...);
}
template<int N, typename F>
__device__ __forceinline__ void sfor(F&& f) {
    sfor_impl(static_cast<F&&>(f), std::make_integer_sequence<int, N>{});
}

// P row value + LDS write (R compile-time -> static xv indices, immediate offsets)
template<int R>
__device__ __forceinline__ void p_emit(ushort* __restrict__ P_sh, int sPart, const float (&xv)[DIMS]) {
    float v;
    if constexpr (R < NPAIR)            v = xv[pid_i0(R)] * xv[pid_i1(R)];
    else if constexpr (R < NPAIR+DIMS)  v = xv[R - NPAIR];
    else if constexpr (R < 154)         v = 1.0f;       // rows 152,153
    else                                v = 0.0f;       // pad
    P_sh[sPart + p_roff(R)] = f2bf(v);
}

// GEMM over M-tiles [MT0, MT0+NMTL) + fused P^T*S epilogue partial.
// A-frag (derived layout): lane l -> m=l&31, k=4*(l>>5)+(e&3)+8*(e>>2)
// C/D (verified m74/m101): col=lane&31, row=(reg&3)+8*(reg>>2)+4*(lane>>5)
template<int MT0, int NMTL>
__device__ __forceinline__ float gemm_half(const ushort* __restrict__ A_sh,
                                           const s16x8 (&bf)[NKK], int lane)
{
    f32x16 acc[NMTL] = {};
    #pragma unroll
    for (int kk = 0; kk < NKK; ++kk) {
        #pragma unroll
        for (int m = 0; m < NMTL; ++m) {
            const s16x8 af = *reinterpret_cast<const s16x8*>(
                A_sh + (size_t)(((kk * NMT) + MT0 + m) * 64 + lane) * 8);
            acc[m] = __builtin_amdgcn_mfma_f32_32x32x16_bf16(af, bf[kk], acc[m], 0, 0, 0);
        }
    }
    // epilogue: multiplier P[row][s] is element (rlo+4*(rhi&1)) of bf[2*(MT0+m)+(rhi>>1)]
    float partial = 0.0f;
    #pragma unroll
    for (int m = 0; m < NMTL; ++m) {
        #pragma unroll
        for (int reg = 0; reg < 16; ++reg) {
            constexpr_if_dummy:;
            const int rlo = reg & 3, rhi = reg >> 2;
            const float mult = bf2f(bf[2 * (MT0 + m) + (rhi >> 1)][rlo + 4 * (rhi & 1)]);
            partial = fmaf(mult, acc[m][reg], partial);
        }
    }
    return partial;
}

// One fused kernel: grid 256 x 512 threads, dynamic LDS 93KB (1 block/CU).
__global__ __launch_bounds__(512, 2)
void poly_logreg_mfma(const float* __restrict__ x,
                      const float* __restrict__ W,
                      const float* __restrict__ b,
                      const float* __restrict__ M_raw,
                      float* __restrict__ out)
{
    extern __shared__ char smem[];
    ushort* A_sh = reinterpret_cast<ushort*>(smem);
    ushort* P_sh = reinterpret_cast<ushort*>(smem + A_BYTES);
    float*  red  = reinterpret_cast<float*>(smem + RED_OFF);

    const int t    = threadIdx.x;
    const int lane = t & 63;
    const int wv   = t >> 6;

    // ---- issue x loads early (sample s = t&127, 4 threads/sample via tg) ----
    const int s  = t & (NB - 1);
    const int tg = t >> 7;                        // 0..3 -> rows [40tg, 40tg+40)
    float xv[DIMS];
    {
        const float4* xp = reinterpret_cast<const float4*>(
            x + ((size_t)blockIdx.x * NB + s) * DIMS);
        #pragma unroll
        for (int q = 0; q < 4; ++q) {
            const float4 v = xp[q];
            xv[q*4+0] = v.x; xv[q*4+1] = v.y; xv[q*4+2] = v.z; xv[q*4+3] = v.w;
        }
    }

    // ---- degree gates ----
    const float M  = 3.0f / (1.0f + __expf(-M_raw[0])) + 1.0f;
    const float g4 = 1.0f / (1.0f + __expf(-10.0f * (M - 3.5f)));
    const float g3 = 1.0f / (1.0f + __expf(-10.0f * (M - 2.5f)));
    const float g2 = 1.0f / (1.0f + __expf(-10.0f * (M - 1.5f)));
    const float g1 = 1.0f / (1.0f + __expf(-10.0f * (M - 0.5f)));

    // ---- build A (bf16, pre-sliced into 32x32x16 A-fragments) ----
    #pragma unroll 2
    for (int i = 0; i < A_ELEMS / 512; ++i) {     // 50 entries/thread
        const int id   = t + (i << 9);
        const int e    = id & 7;
        const int ln   = (id >> 3) & 63;
        const int mtkk = id >> 9;
        const int mt   = mtkk % NMT, kk = mtkk / NMT;
        const int row  = mt * 32 + (ln & 31);
        const int k    = kk * 16 + 4 * (ln >> 5) + (e & 3) + 8 * (e >> 2);
        const RowMeta rm = ROWTAB.m[row];
        float v = 0.0f;
        if ((unsigned)(k - rm.qs) < (unsigned)(rm.qe - rm.qs)) {
            const float g = rm.gs == 0 ? g4 : rm.gs == 1 ? g3 : rm.gs == 2 ? g2
                          : rm.gs == 3 ? g1 : 0.0f;
            v = g * W[rm.wb + (k - rm.qs)];
        }
        A_sh[id] = f2bf(v);
    }

    // ---- build P (pair products etc.), rows [40tg, 40tg+40) for sample s ----
    {
        const int sPart = ((s >> 5) << 9) + ((s & 31) << 3);
        switch (tg) {
            case 0: sfor<40>([&](auto K){ p_emit<decltype(K)::value +   0>(P_sh, sPart, xv); }); break;
            case 1: sfor<40>([&](auto K){ p_emit<decltype(K)::value +  40>(P_sh, sPart, xv); }); break;
            case 2: sfor<40>([&](auto K){ p_emit<decltype(K)::value +  80>(P_sh, sPart, xv); }); break;
            default:sfor<40>([&](auto K){ p_emit<decltype(K)::value + 120>(P_sh, sPart, xv); }); break;
        }
    }
    __syncthreads();

    // ---- GEMM: wave wv -> (nt = wv&3, mh = wv>>2) ----
    const int nt = wv & 3;
    s16x8 bf[NKK];
    #pragma unroll
    for (int kk = 0; kk < NKK; ++kk)
        bf[kk] = *reinterpret_cast<const s16x8*>(P_sh + (size_t)((kk * NNT + nt) * 64 + lane) * 8);

    float partial = (wv >> 2) ? gemm_half<3, 2>(A_sh, bf, lane)
                              : gemm_half<0, 3>(A_sh, bf, lane);
    partial += __shfl_xor(partial, 32, 64);       // sum the two row-halves (lane^32)

    if (lane < 32) red[wv * 32 + lane] = partial;
    __syncthreads();

    // ---- finalize: 128 samples ----
    if (t < NB) {
        const int c = t & 31, ntf = t >> 5;
        float logit = red[ntf * 32 + c] + red[(ntf + 4) * 32 + c] + W[0] + b[0];
        out[(size_t)blockIdx.x * NB + t] = 1.0f / (1.0f + __expf(-logit));
    }
}

extern "C" void kernel_launch(void* const* d_in, const int* in_sizes, int n_in,
                              void* d_out, int out_size, void* d_ws, size_t ws_size,
                              hipStream_t stream)
{
    const float* x     = (const float*)d_in[0];
    const float* W     = (const float*)d_in[1];
    const float* b     = (const float*)d_in[2];
    const float* M_raw = (const float*)d_in[3];
    float* out = (float*)d_out;

    poly_logreg_mfma<<<BATCH / NB, 512, LDS_BYTES, stream>>>(x, W, b, M_raw, out);
}

// Round 4
// 17.440 us; speedup vs baseline: 2.1364x; 2.1364x over previous
//
#include <hip/hip_runtime.h>
#include <math.h>
#include <utility>

#define DIMS  16
#define BATCH 32768
#define NPAIR 136
#define NROLE 4

typedef float f32x4 __attribute__((ext_vector_type(4)));

// ---------- compile-time combinatorics (lex = combinations_with_replacement) ----------
constexpr int pairlex(int i0, int i1){ int s=0; for(int j=0;j<i0;++j) s+=(DIMS-j); return s+(i1-i0); }
constexpr int pid_i0(int pid){ int i0=0,rem=pid; while(rem>=DIMS-i0){rem-=DIMS-i0;++i0;} return i0; }
constexpr int pid_i1(int pid){ int i0=0,rem=pid; while(rem>=DIMS-i0){rem-=DIMS-i0;++i0;} return i0+rem; }
constexpr int cnt3(int j){ return (DIMS-j)*(DIMS+1-j)/2; }
constexpr int off3(int i0){ int s=0; for(int j=0;j<i0;++j) s+=cnt3(j); return s; }
constexpr int cnt4j(int j){ return (DIMS-j)*(DIMS+1-j)*(DIMS+2-j)/6; }
constexpr int off4(int i0){ int s=0; for(int j=0;j<i0;++j) s+=cnt4j(j); return s; }
// W layout: [0]=const, [1..16]=deg1, [17..152]=deg2, [153..968]=deg3, [969..4844]=deg4
constexpr int w3base(int i0,int i1){ int s=off3(i0); for(int b=i0;b<i1;++b) s+=(DIMS-b); return 1+DIMS+NPAIR+s; }
constexpr int w4base(int i0,int i1){ int s=off4(i0); for(int b=i0;b<i1;++b) s+=cnt3(b); return 1+DIMS+NPAIR+816+s; }
static_assert(pairlex(15,15)==135 && off3(DIMS)==816 && off4(DIMS)==3876, "combi");
static_assert(w3base(15,15)==968 && w4base(15,15)==4844, "wtail");

// ---------- padded LDS layout: per pair [W2,W3run]pad4 then [W4run]pad4; then W1 ----------
constexpr int align4(int n){ return (n+3)&~3; }
constexpr int TRI(int n){ return n*(n+1)/2; }
struct Layout { int w23[NPAIR]; int w4[NPAIR]; int w1; int total; };
constexpr Layout make_layout(){
    Layout L{}; int cur=0;
    for(int p=0;p<NPAIR;++p){
        int i1=pid_i1(p);
        L.w23[p]=cur; cur+=align4(17-i1);          // [W2, W3 x (16-i1)] padded
        L.w4[p]=cur;  cur+=align4(TRI(16-i1));     // W4 suffix block padded
    }
    L.w1=cur; cur+=DIMS; L.total=cur;
    return L;
}
inline constexpr Layout LAY = make_layout();
#define PADTOT 5272
static_assert(LAY.total==PADTOT, "padtot");

// ---------- staging descriptor: slot -> (gate-degree<<13 | W src index); 0 = pad ----------
struct DescT { unsigned short d[PADTOT]; };
constexpr DescT make_desc(){
    DescT D{};                                     // zero-init: pad slots -> deg0 -> value 0
    for(int p=0;p<NPAIR;++p){
        int i0=pid_i0(p), i1=pid_i1(p);
        D.d[LAY.w23[p]] = (unsigned short)((2u<<13) | (unsigned)(1+DIMS+p));
        for(int j=0;j<DIMS-i1;++j)
            D.d[LAY.w23[p]+1+j] = (unsigned short)((3u<<13) | (unsigned)(w3base(i0,i1)+j));
        int k=w4base(i0,i1), idx=LAY.w4[p];
        for(int i2=i1;i2<DIMS;++i2)
            for(int i3=i2;i3<DIMS;++i3)
                D.d[idx++] = (unsigned short)((4u<<13) | (unsigned)(k++));
    }
    for(int i=0;i<DIMS;++i) D.d[LAY.w1+i] = (unsigned short)((1u<<13) | (unsigned)(1+i));
    return D;
}
__device__ __constant__ DescT DESC = make_desc();

// ---------- LPT partition of the 136 pairs into 4 balanced roles ----------
constexpr int costv(int v){ return (DIMS-v) + (DIMS+1-v)*(DIMS+2-v)/2 + 3; }
struct Plan { int role_of[NPAIR]; int d1_role; };
constexpr Plan make_plan(){
    Plan p{}; long load[NROLE]={};
    for(int v=0; v<DIMS; ++v)                      // costs descend in v -> LPT order
        for(int i0=0; i0<=v; ++i0){
            int best=0;
            for(int r=1;r<NROLE;++r) if(load[r]<load[best]) best=r;
            p.role_of[pairlex(i0,v)]=best;
            load[best]+=costv(v);
        }
    int best=0;
    for(int r=1;r<NROLE;++r) if(load[r]<load[best]) best=r;
    p.d1_role=best;
    return p;
}
inline constexpr Plan PLAN = make_plan();

// ---------- static_for ----------
template<typename F, int... Is>
__device__ __forceinline__ void sfor_impl(F&& f, std::integer_sequence<int,Is...>){
    (f(std::integral_constant<int,Is>{}), ...);
}
template<int N, typename F>
__device__ __forceinline__ void sfor(F&& f){
    sfor_impl(static_cast<F&&>(f), std::make_integer_sequence<int,N>{});
}

// ---------- per-pair term: a += p2 * (W2h + sum W3h*x + sum_i2 x_i2 * sum_i3 W4h*x_i3) ----------
// All W reads: ds_read_b128 broadcast at compile-time offsets; all x indices compile-time.
template<int PID>
__device__ __forceinline__ void pair_term(const float* __restrict__ Wl,
                                          const float (&xv)[DIMS], float& a)
{
    constexpr int i0=pid_i0(PID), i1=pid_i1(PID);
    constexpr int B23=LAY.w23[PID], B4=LAY.w4[PID];
    constexpr int N3 = DIMS-i1;
    constexpr int NQ23 = align4(17-i1)/4;

    f32x4 q23[NQ23];
    sfor<NQ23>([&](auto C){ constexpr int c=decltype(C)::value;
        q23[c] = *reinterpret_cast<const f32x4*>(Wl + B23 + 4*c); });

    float s3 = q23[0][0];                          // gated W2, folded into the dot
    sfor<N3>([&](auto J){ constexpr int j=decltype(J)::value;
        constexpr int e = 1+j;
        s3 = fmaf(q23[e/4][e%4], xv[i1+j], s3); });

    float t = 0.f;
    f32x4 cq{};
    sfor<N3>([&](auto I){ constexpr int i2 = i1 + decltype(I)::value;
        float s4 = 0.f;
        sfor<DIMS-i2>([&](auto K){ constexpr int i3 = i2 + decltype(K)::value;
            constexpr int e = ((DIMS-i1)+(DIMS+1-i2))*(i2-i1)/2 + (i3-i2); // global pos in W4 block
            if constexpr ((e&3)==0)
                cq = *reinterpret_cast<const f32x4*>(Wl + B4 + e);
            s4 = fmaf(cq[e&3], xv[i3], s4); });
        t = fmaf(xv[i2], s4, t); });

    a = fmaf(xv[i0]*xv[i1], s3 + t, a);
}

template<int R>
__device__ __forceinline__ float role_body(const float* __restrict__ Wl,
                                           const float (&xv)[DIMS])
{
    float a = 0.f;
    sfor<NPAIR>([&](auto P){ constexpr int pid=decltype(P)::value;
        if constexpr (PLAN.role_of[pid]==R) pair_term<pid>(Wl, xv, a); });
    if constexpr (R==PLAN.d1_role){
        sfor<4>([&](auto C){ constexpr int c=decltype(C)::value;
            const f32x4 q = *reinterpret_cast<const f32x4*>(Wl + LAY.w1 + 4*c);
            a = fmaf(q[0], xv[4*c+0], a); a = fmaf(q[1], xv[4*c+1], a);
            a = fmaf(q[2], xv[4*c+2], a); a = fmaf(q[3], xv[4*c+3], a); });
    }
    return a;
}

// Block = 512 threads = 8 waves = 4 roles x 2 sample-groups (128 samples/block).
// Grid = 256 -> 1 block/CU, 2 waves/SIMD. W staged once per block into LDS, gates folded.
__global__ __launch_bounds__(512, 2)
void poly_logreg_v4(const float* __restrict__ x, const float* __restrict__ W,
                    const float* __restrict__ b, const float* __restrict__ M_raw,
                    float* __restrict__ out)
{
    __shared__ __align__(16) float Wl[PADTOT];
    __shared__ float red[8][64];

    const int t = threadIdx.x, lane = t & 63, wv = t >> 6;
    const int role = wv & 3, grp = wv >> 2;
    const int s = (blockIdx.x << 7) + (grp << 6) + lane;

    // issue x loads first (hide under staging)
    const float4* xp = reinterpret_cast<const float4*>(x + (size_t)s * DIMS);
    const float4 xa = xp[0], xb = xp[1], xc = xp[2], xd = xp[3];

    // degree gates (uniform scalars)
    const float M  = 3.0f/(1.0f+__expf(-M_raw[0])) + 1.0f;
    const float g1 = 1.0f/(1.0f+__expf(-10.0f*(M-0.5f)));
    const float g2 = 1.0f/(1.0f+__expf(-10.0f*(M-1.5f)));
    const float g3 = 1.0f/(1.0f+__expf(-10.0f*(M-2.5f)));
    const float g4 = 1.0f/(1.0f+__expf(-10.0f*(M-3.5f)));

    // stage gate-folded, padded W into LDS (coalesced desc reads + gathered W, L2-hit)
    for (int i = t; i < PADTOT; i += 512){
        const unsigned short d = DESC.d[i];
        const int deg = d >> 13, src = d & 0x1FFF;
        const float gv = (deg==4)?g4 : (deg==3)?g3 : (deg==2)?g2 : (deg==1)?g1 : 0.0f;
        Wl[i] = gv * W[src];
    }

    float xv[DIMS];
    xv[0]=xa.x; xv[1]=xa.y; xv[2]=xa.z; xv[3]=xa.w;
    xv[4]=xb.x; xv[5]=xb.y; xv[6]=xb.z; xv[7]=xb.w;
    xv[8]=xc.x; xv[9]=xc.y; xv[10]=xc.z; xv[11]=xc.w;
    xv[12]=xd.x; xv[13]=xd.y; xv[14]=xd.z; xv[15]=xd.w;

    __syncthreads();

    float a;
    switch (role){
        case 0:  a = role_body<0>(Wl, xv); break;
        case 1:  a = role_body<1>(Wl, xv); break;
        case 2:  a = role_body<2>(Wl, xv); break;
        default: a = role_body<3>(Wl, xv); break;
    }

    red[wv][lane] = a;
    __syncthreads();

    if (t < 128){
        const int g = t >> 6, l = t & 63;
        const float logit = red[4*g+0][l] + red[4*g+1][l] + red[4*g+2][l] + red[4*g+3][l]
                          + W[0] + b[0];
        out[((size_t)blockIdx.x << 7) + t] = 1.0f/(1.0f+__expf(-logit));
    }
}

extern "C" void kernel_launch(void* const* d_in, const int* in_sizes, int n_in,
                              void* d_out, int out_size, void* d_ws, size_t ws_size,
                              hipStream_t stream)
{
    const float* x     = (const float*)d_in[0];
    const float* W     = (const float*)d_in[1];
    const float* b     = (const float*)d_in[2];
    const float* M_raw = (const float*)d_in[3];
    float* out = (float*)d_out;

    poly_logreg_v4<<<BATCH/128, 512, 0, stream>>>(x, W, b, M_raw, out);
}